// Round 10
// baseline (400.522 us; speedup 1.0000x reference)
//
#include <hip/hip_runtime.h>
#include <hip/hip_bf16.h>
#include <math.h>

#define S_LEN 2048
#define HID 3072
#define NHEAD 32
#define NKV 8
#define HDIM 96
#define QKV_N 4608   // 32*96 + 2*8*96
#define NB 32        // S/64 blocks
#define GHDIM 128
#define KOFF 3072    // K section start col
#define VOFF 3840    // V section start col

typedef __attribute__((ext_vector_type(8))) short bf16x8;
typedef __attribute__((ext_vector_type(4))) short bf16x4;
typedef __attribute__((ext_vector_type(4))) float f32x4;
typedef unsigned short ushort_t;

// 1/sqrt(96) * log2(e): Q pre-scaled so softmax runs in exp2 domain
#define SCALE2 0.14724444754f

__device__ __forceinline__ unsigned short f2bf(float x) {
    unsigned u = __float_as_uint(x);
    u += 0x7fffu + ((u >> 16) & 1u);
    return (unsigned short)(u >> 16);
}
__device__ __forceinline__ unsigned packbf2(float a, float b) {
    return (unsigned)f2bf(a) | ((unsigned)f2bf(b) << 16);
}
__device__ __forceinline__ float bf2f(ushort_t u) {
    return __uint_as_float(((unsigned)u) << 16);
}

#define GLOBAL_AS __attribute__((address_space(1)))
#define LDS_AS __attribute__((address_space(3)))
__device__ __forceinline__ void gl_lds16(const void* g, void* l) {
    __builtin_amdgcn_global_load_lds((const GLOBAL_AS unsigned int*)g,
                                     (LDS_AS unsigned int*)l, 16, 0, 0);
}
__device__ __forceinline__ void barrier_raw() {
    asm volatile("s_barrier" ::: "memory");
}

// ============ bf16 MFMA GEMM: A[M,K] @ Bt[N,K]^T ============
// v7: clean A/B of R3 minus its confound. R3 (dbuf+vmcnt(8)+XCD swizzle) was
//     111us with FETCH 144MB — the swizzle destroyed B-panel L2 reuse. This is
//     dbuf-64KB + DEFAULT mapping + counted vmcnt(8): per-step staging latency
//     (B misses L2: 89MB/77.9us = 1.15 TB/s, ~HBM latency exposed 48x by the
//     single-buffer vmcnt(0) drain) is hidden by one-step-ahead prefetch.
// mode 0: C f32. mode 1 (QKV): Cbf bf16 [M,N]; K-section cols also f32 -> CfK.
__global__ __launch_bounds__(256, 4) void gemm_bf16(const ushort_t* __restrict__ A,
                                                    const ushort_t* __restrict__ Bt,
                                                    float* __restrict__ C,
                                                    ushort_t* __restrict__ Cbf,
                                                    float* __restrict__ CfK,
                                                    int M, int N, int K, int mode) {
    __shared__ ushort_t As[2][128 * 64];
    __shared__ ushort_t Bs[2][128 * 64];
    const int tid = threadIdx.x;
    const int lane = tid & 63;
    const int w = tid >> 6;
    const int wm = (w >> 1) * 64;
    const int wn = (w & 1) * 64;
    const int l15 = lane & 15;
    const int quad = lane >> 4;
    const int m0 = blockIdx.y * 128;
    const int n0 = blockIdx.x * 128;

    f32x4 acc[4][4] = {};

    auto stage = [&](int k0, int buf) {
#pragma unroll
        for (int j = 0; j < 4; ++j) {
            int s = j * 256 + w * 64 + lane;
            int row = s >> 3;
            int kc = (s & 7) ^ (row & 7);
            gl_lds16(A + (size_t)(m0 + row) * K + k0 + kc * 8,
                     &As[buf][(j * 256 + w * 64) * 8]);
        }
#pragma unroll
        for (int j = 0; j < 4; ++j) {
            int s = j * 256 + w * 64 + lane;
            int row = s >> 3;
            int kc = (s & 7) ^ (row & 7);
            gl_lds16(Bt + (size_t)(n0 + row) * K + k0 + kc * 8,
                     &Bs[buf][(j * 256 + w * 64) * 8]);
        }
    };

    stage(0, 0);
    int cur = 0;

    for (int k0 = 0; k0 < K; k0 += 64) {
        if (k0 + 64 < K) {
            stage(k0 + 64, cur ^ 1);
            // 8 newest (next tile) stay in flight; current tile landed
            asm volatile("s_waitcnt vmcnt(8)" ::: "memory");
        } else {
            asm volatile("s_waitcnt vmcnt(0)" ::: "memory");
        }
        barrier_raw();   // all waves' portions of buf[cur] landed

        const ushort_t* Asc = As[cur];
        const ushort_t* Bsc = Bs[cur];
        bf16x8 af[2][4], bf[2][4];
#pragma unroll
        for (int mt = 0; mt < 4; ++mt) {
            int row = wm + mt * 16 + l15;
            int rx = row & 7;
#pragma unroll
            for (int ph = 0; ph < 2; ++ph)
                af[ph][mt] = *(const bf16x8*)&Asc[(row * 8 + ((ph * 4 + quad) ^ rx)) * 8];
        }
#pragma unroll
        for (int nt = 0; nt < 4; ++nt) {
            int row = wn + nt * 16 + l15;
            int rx = row & 7;
#pragma unroll
            for (int ph = 0; ph < 2; ++ph)
                bf[ph][nt] = *(const bf16x8*)&Bsc[(row * 8 + ((ph * 4 + quad) ^ rx)) * 8];
        }
#pragma unroll
        for (int ph = 0; ph < 2; ++ph)
#pragma unroll
            for (int mt = 0; mt < 4; ++mt)
#pragma unroll
                for (int nt = 0; nt < 4; ++nt)
                    acc[mt][nt] = __builtin_amdgcn_mfma_f32_16x16x32_bf16(
                        af[ph][mt], bf[ph][nt], acc[mt][nt], 0, 0, 0);

        barrier_raw();   // reads of buf[cur] done; safe to overwrite next iter
        cur ^= 1;
    }

    if (mode == 0) {
#pragma unroll
        for (int mt = 0; mt < 4; ++mt)
#pragma unroll
            for (int nt = 0; nt < 4; ++nt)
#pragma unroll
                for (int r = 0; r < 4; ++r) {
                    int row = m0 + wm + mt * 16 + quad * 4 + r;
                    int col = n0 + wn + nt * 16 + l15;
                    C[(size_t)row * N + col] = acc[mt][nt][r];
                }
    } else {
        const bool isK = (n0 >= KOFF) && (n0 < VOFF);
#pragma unroll
        for (int mt = 0; mt < 4; ++mt)
#pragma unroll
            for (int nt = 0; nt < 4; ++nt)
#pragma unroll
                for (int r = 0; r < 4; ++r) {
                    int row = m0 + wm + mt * 16 + quad * 4 + r;
                    int col = n0 + wn + nt * 16 + l15;
                    Cbf[(size_t)row * N + col] = f2bf(acc[mt][nt][r]);
                    if (isK) CfK[(size_t)row * 768 + col - KOFF] = acc[mt][nt][r];
                }
    }
}

// ---------------- shared bodies for fused prep kernels ------------------------
__device__ __forceinline__ void conv_body(const float* __restrict__ X,
                                          ushort_t* __restrict__ Y, int i) {
    const float4 v = *(const float4*)(X + (size_t)i * 4);
    int2 p;
    p.x = (int)packbf2(v.x, v.y);
    p.y = (int)packbf2(v.z, v.w);
    *(int2*)(Y + (size_t)i * 4) = p;
}

__device__ __forceinline__ void transpose_body(const float* __restrict__ W,
                                               ushort_t* __restrict__ Wt,
                                               int K, int N, int k0, int n0, int tid) {
    __shared__ float Ts[64][65];
    {
        int r = tid >> 2, cq = tid & 3;
#pragma unroll
        for (int i = 0; i < 4; ++i) {
            int c = cq * 16 + i * 4;
            const float4 v = *(const float4*)(W + (size_t)(k0 + r) * N + n0 + c);
            Ts[r][c] = v.x; Ts[r][c + 1] = v.y; Ts[r][c + 2] = v.z; Ts[r][c + 3] = v.w;
        }
    }
    __syncthreads();
#pragma unroll
    for (int it = 0; it < 2; ++it) {
        int n = (tid >> 3) + it * 32;
        int kc = tid & 7;
        int4 r;
        r.x = (int)(packbf2(Ts[kc * 8 + 0][n], Ts[kc * 8 + 1][n]));
        r.y = (int)(packbf2(Ts[kc * 8 + 2][n], Ts[kc * 8 + 3][n]));
        r.z = (int)(packbf2(Ts[kc * 8 + 4][n], Ts[kc * 8 + 5][n]));
        r.w = (int)(packbf2(Ts[kc * 8 + 6][n], Ts[kc * 8 + 7][n]));
        *(int4*)(Wt + (size_t)(n0 + n) * K + k0 + kc * 8) = r;
    }
}

// prep1: hidden f32->bf16 (blocks 0..6143) + qkv_w transpose (blocks 6144..9599)
__global__ __launch_bounds__(256) void prep1(const float* __restrict__ hidden,
                                             ushort_t* __restrict__ h_bf,
                                             const float* __restrict__ qkv_w,
                                             ushort_t* __restrict__ w1t) {
    int id = blockIdx.x;
    int tid = threadIdx.x;
    if (id < 6144) {
        conv_body(hidden, h_bf, id * 256 + tid);
    } else {
        int r = id - 6144;              // 72 x 48
        transpose_body(qkv_w, w1t, HID, QKV_N, (r / 72) * 64, (r % 72) * 64, tid);
    }
}

// prep2: RoPE q/k from bf16 qkv (0..15359) + V transpose (15360..15615)
//        (o_w transpose moved into pool_gate launch — overlaps with gate pools)
__global__ __launch_bounds__(256) void prep2(const ushort_t* __restrict__ qkv_bf,
                                             const float* __restrict__ cosb,
                                             const float* __restrict__ sinb,
                                             ushort_t* __restrict__ Qb,
                                             ushort_t* __restrict__ Kb,
                                             ushort_t* __restrict__ Vtb) {
    int id = blockIdx.x;
    int tid = threadIdx.x;
    if (id < 15360) {
        int idx = id * 256 + tid;   // S*40*48
        int d = idx % 48;
        int tmp = idx / 48;
        int head = tmp % 40;
        int s = tmp / 40;
        float c0 = cosb[s * 96 + d], c1 = cosb[s * 96 + d + 48];
        float s0 = sinb[s * 96 + d], s1 = sinb[s * 96 + d + 48];
        if (head < 32) {
            size_t base = (size_t)s * QKV_N + head * 96;
            float x0 = bf2f(qkv_bf[base + d]), x1 = bf2f(qkv_bf[base + d + 48]);
            size_t ob = (size_t)s * HID + head * 96;
            Qb[ob + d] = f2bf((x0 * c0 - x1 * s0) * SCALE2);
            Qb[ob + d + 48] = f2bf((x1 * c1 + x0 * s1) * SCALE2);
        } else {
            int hh = head - 32;
            size_t base = (size_t)s * QKV_N + KOFF + hh * 96;
            float x0 = bf2f(qkv_bf[base + d]), x1 = bf2f(qkv_bf[base + d + 48]);
            size_t ob = ((size_t)hh * S_LEN + s) * 96;
            Kb[ob + d] = f2bf(x0 * c0 - x1 * s0);
            Kb[ob + d + 48] = f2bf(x1 * c1 + x0 * s1);
        }
    } else {
        int r = id - 15360;
        int ibk = r & 31, h = r >> 5;
        __shared__ ushort_t Vs[64][104];   // 208B rows, 16B aligned
        {
            int rr = tid >> 2, seg = tid & 3;
#pragma unroll
            for (int j = 0; j < 3; ++j) {
                int c = seg * 24 + j * 8;
                const int4 v = *(const int4*)(qkv_bf + (size_t)(ibk * 64 + rr) * QKV_N +
                                              VOFF + h * 96 + c);
                *(int4*)&Vs[rr][c] = v;
            }
        }
        __syncthreads();
#pragma unroll
        for (int it = 0; it < 3; ++it) {
            int s = tid + it * 256;       // 768 = 96 d x 8 tc
            int d = s >> 3, tc = s & 7;
            int4 o;
            o.x = (int)Vs[tc * 8 + 0][d] | ((int)Vs[tc * 8 + 1][d] << 16);
            o.y = (int)Vs[tc * 8 + 2][d] | ((int)Vs[tc * 8 + 3][d] << 16);
            o.z = (int)Vs[tc * 8 + 4][d] | ((int)Vs[tc * 8 + 5][d] << 16);
            o.w = (int)Vs[tc * 8 + 6][d] | ((int)Vs[tc * 8 + 7][d] << 16);
            *(int4*)(Vtb + ((size_t)h * 96 + d) * S_LEN + ibk * 64 + tc * 8) = o;
        }
    }
}

// ---------------- fused pools + gate GEMVs + o_w transpose --------------------
// blocks 0..255: pools+GEMVs (nb=id&31, h=id>>5). blocks 256..2559: o_w
// transpose (independent of pools; overlaps the latency-bound gate blocks).
__global__ __launch_bounds__(256) void pool_gate_kernel(const float* __restrict__ qkvK,
                                                        const ushort_t* __restrict__ qkv_bf,
                                                        const float* __restrict__ gate_wk,
                                                        const float* __restrict__ gate_wq,
                                                        float* __restrict__ k_gate,
                                                        float* __restrict__ q_gate,
                                                        const float* __restrict__ o_w,
                                                        ushort_t* __restrict__ o_wt) {
    int id = blockIdx.x;
    int tid = threadIdx.x;
    if (id >= 256) {
        int r = id - 256;               // 48 x 48
        transpose_body(o_w, o_wt, HID, HID, (r / 48) * 64, (r % 48) * 64, tid);
        return;
    }
    int nb = id & 31, h = id >> 5;
    __shared__ float poolk[192];
    __shared__ float poolq[96];
    __shared__ float poolq2[8][96];
    if (tid < 128) {
        if (tid < 96) {
            float s = 0.f, mx = -1e30f;
            for (int i = 0; i < 64; i++) {
                float v = qkvK[(size_t)(nb * 64 + i) * 768 + h * 96 + tid];
                s += v;
                mx = fmaxf(mx, v);
            }
            poolk[tid] = s * (1.f / 64.f);
            poolk[96 + tid] = mx;
        }
    } else {
        int t2 = tid - 128;
        if (t2 < 96) {
            int o = t2 % 12;       // element octet (8 bf16)
            int hf = t2 / 12;      // i-range hf*8 .. hf*8+7
            float part[8] = {};
            for (int ii = 0; ii < 8; ++ii) {
                int i = hf * 8 + ii;
                const ushort_t* rp = qkv_bf + (size_t)(nb * 64 + i) * QKV_N +
                                     h * 4 * 96 + o * 8;
#pragma unroll
                for (int g = 0; g < 4; ++g) {
                    bf16x8 v = *(const bf16x8*)(rp + g * 96);
#pragma unroll
                    for (int j = 0; j < 8; ++j) part[j] += bf2f((ushort_t)v[j]);
                }
            }
#pragma unroll
            for (int j = 0; j < 8; ++j) poolq2[hf][o * 8 + j] = part[j];
        }
    }
    __syncthreads();
    if (tid >= 128 && tid < 224) {
        int t2 = tid - 128;
        float s = 0.f;
#pragma unroll
        for (int hf = 0; hf < 8; ++hf) s += poolq2[hf][t2];
        poolq[t2] = s * (1.f / 256.f);
    }
    __syncthreads();
    if (tid < 128) {
        float acc = 0.f;
        for (int e = 0; e < 192; e++) acc += poolk[e] * gate_wk[e * GHDIM + tid];
        k_gate[(size_t)(nb * NKV + h) * GHDIM + tid] = acc;
    } else {
        int t2 = tid - 128;
        float acc = 0.f;
        for (int e = 0; e < 96; e++) acc += poolq[e] * gate_wq[e * GHDIM + t2];
        q_gate[(size_t)(nb * NKV + h) * GHDIM + t2] = acc;
    }
}

// ---------------- block gate logits -> softmax -> threshold mask --------------
// v2: 256 threads; 8 lanes per kv-block dot (16 MACs each + shfl_xor reduce)
__global__ __launch_bounds__(256) void blockmask_kernel(const float* __restrict__ q_gate,
                                                        const float* __restrict__ k_gate,
                                                        int* __restrict__ mask) {
    int h = blockIdx.x, qb = blockIdx.y;
    int tid = threadIdx.x;
    __shared__ float logits[32];
    int kb = tid >> 3, e8 = tid & 7;
    float acc = 0.f;
    if (kb <= qb) {
        const float* qg = &q_gate[(size_t)(qb * NKV + h) * GHDIM];
        const float* kg = &k_gate[(size_t)(kb * NKV + h) * GHDIM];
#pragma unroll
        for (int i = 0; i < 16; ++i) {
            int e = e8 * 16 + i;
            acc += qg[e] * kg[e];
        }
    }
    acc += __shfl_xor(acc, 1);
    acc += __shfl_xor(acc, 2);
    acc += __shfl_xor(acc, 4);
    if (e8 == 0) logits[kb] = (kb <= qb) ? acc * 0.08838834764831845f : -1e30f;
    __syncthreads();
    if (tid < 32) {
        float mx = -1e30f;
        for (int j = 0; j <= qb; j++) mx = fmaxf(mx, logits[j]);
        float sum = 0.f;
        for (int j = 0; j <= qb; j++) sum += __expf(logits[j] - mx);
        float p = (tid <= qb) ? __expf(logits[tid] - mx) / sum : 0.f;
        int m = ((p >= 0.03f) && (tid <= qb)) || (tid == qb);
        mask[(h * NB + qb) * NB + tid] = m;
    }
}

// ============ MFMA block-sparse flash attention v3 + T5 setprio ========
__global__ __launch_bounds__(256) void attn_mfma(const ushort_t* __restrict__ Qb,
                                                 const ushort_t* __restrict__ Kb,
                                                 const ushort_t* __restrict__ Vtb,
                                                 const int* __restrict__ mask,
                                                 ushort_t* __restrict__ out) {
    const int hq = blockIdx.x;
    const int ib = NB - 1 - (int)blockIdx.y;
    const int h = hq >> 2;
    const int tid = threadIdx.x;
    const int lane = tid & 63;
    const int w = tid >> 6;
    const int l15 = lane & 15;
    const int quad = lane >> 4;

    __shared__ ushort_t KsL[2][64 * 96];
    __shared__ ushort_t VtL[2][96 * 64];

    int pk[3];
    {
        int b0 = quad + (l15 & 7);
#pragma unroll
        for (int ks = 0; ks < 3; ++ks) {
            int p = b0 + ks * 4;
            if (p >= 12) p -= 12;
            if (p >= 12) p -= 12;
            pk[ks] = p;
        }
    }

    bf16x8 qf[3];
    {
        const ushort_t* qp = Qb + (size_t)(ib * 64 + w * 16 + l15) * HID + hq * 96;
#pragma unroll
        for (int ks = 0; ks < 3; ++ks)
            qf[ks] = *(const bf16x8*)(qp + ks * 32 + quad * 8);
    }

    const ushort_t* kbase = Kb + (size_t)h * S_LEN * 96;
    const ushort_t* vbase = Vtb + (size_t)h * 96 * S_LEN;

    unsigned long long bits =
        __ballot((lane <= ib) && (mask[(h * NB + ib) * NB + (lane & 31)] != 0));

    float m_i = -1e30f, l_i = 0.f;
    f32x4 acc_o[6] = {};

    auto stage = [&](int jb, int buf) {
#pragma unroll
        for (int j = 0; j < 3; ++j) {
            int s = j * 256 + w * 64 + lane;
            int t = (s * 2731) >> 15;
            int cpos = s - t * 12;
            int c = cpos - (t & 7);
            if (c < 0) c += 12;
            gl_lds16(kbase + (size_t)(jb * 64 + t) * 96 + c * 8,
                     &KsL[buf][(j * 256 + w * 64) * 8]);
        }
#pragma unroll
        for (int j = 0; j < 3; ++j) {
            int s = j * 256 + w * 64 + lane;
            int d = s >> 3;
            int tc = (s & 7) ^ (d & 7);
            gl_lds16(vbase + (size_t)d * S_LEN + jb * 64 + tc * 8,
                     &VtL[buf][(j * 256 + w * 64) * 8]);
        }
    };

    int jb = (int)__builtin_ctzll(bits);
    bits &= bits - 1;
    stage(jb, 0);
    int cur = 0;

    while (true) {
        int jn = -1;
        if (bits) {
            jn = (int)__builtin_ctzll(bits);
            bits &= bits - 1;
        }
        if (jn >= 0) {
            stage(jn, cur ^ 1);
            asm volatile("s_waitcnt vmcnt(6)" ::: "memory");
        } else {
            asm volatile("s_waitcnt vmcnt(0)" ::: "memory");
        }
        barrier_raw();

        const ushort_t* Kc = KsL[cur];
        const ushort_t* Vc = VtL[cur];

        f32x4 st[4] = {};
        __builtin_amdgcn_s_setprio(1);
#pragma unroll
        for (int ks = 0; ks < 3; ++ks)
#pragma unroll
            for (int nt = 0; nt < 4; ++nt) {
                bf16x8 kb = *(const bf16x8*)&Kc[(nt * 16 + l15) * 96 + pk[ks] * 8];
                st[nt] = __builtin_amdgcn_mfma_f32_16x16x32_bf16(kb, qf[ks], st[nt], 0, 0, 0);
            }
        __builtin_amdgcn_s_setprio(0);
        if (jb == ib) {
            int q = w * 16 + l15;
#pragma unroll
            for (int nt = 0; nt < 4; ++nt)
#pragma unroll
                for (int r = 0; r < 4; ++r)
                    if ((nt * 16 + quad * 4 + r) > q) st[nt][r] = -1e30f;
        }
        float mx = -1e30f;
#pragma unroll
        for (int nt = 0; nt < 4; ++nt)
#pragma unroll
            for (int r = 0; r < 4; ++r) mx = fmaxf(mx, st[nt][r]);
        mx = fmaxf(mx, __shfl_xor(mx, 16));
        mx = fmaxf(mx, __shfl_xor(mx, 32));
        float mnew = fmaxf(m_i, mx);
        float alpha = __builtin_amdgcn_exp2f(m_i - mnew);
        float ps = 0.f;
#pragma unroll
        for (int nt = 0; nt < 4; ++nt)
#pragma unroll
            for (int r = 0; r < 4; ++r) {
                float p = __builtin_amdgcn_exp2f(st[nt][r] - mnew);
                st[nt][r] = p;
                ps += p;
            }
        ps += __shfl_xor(ps, 16);
        ps += __shfl_xor(ps, 32);
        l_i = l_i * alpha + ps;
        m_i = mnew;
#pragma unroll
        for (int t = 0; t < 6; ++t)
#pragma unroll
            for (int r = 0; r < 4; ++r) acc_o[t][r] *= alpha;
        bf16x4 pf[4];
#pragma unroll
        for (int kblk = 0; kblk < 4; ++kblk) {
            union { bf16x4 v; unsigned u[2]; } pb;
            pb.u[0] = packbf2(st[kblk][0], st[kblk][1]);
            pb.u[1] = packbf2(st[kblk][2], st[kblk][3]);
            pf[kblk] = pb.v;
        }
        __builtin_amdgcn_s_setprio(1);
#pragma unroll
        for (int kblk = 0; kblk < 4; ++kblk) {
            int cchunk = kblk * 2 + (quad >> 1);
            int eoff = (quad & 1) * 4;
#pragma unroll
            for (int dt = 0; dt < 6; ++dt) {
                int d = dt * 16 + l15;
                bf16x4 vf = *(const bf16x4*)&Vc[(d * 8 + (cchunk ^ (d & 7))) * 8 + eoff];
                acc_o[dt] = __builtin_amdgcn_mfma_f32_16x16x16bf16_1k(
                    vf, pf[kblk], acc_o[dt], 0, 0, 0);
            }
        }
        __builtin_amdgcn_s_setprio(0);

        if (jn < 0) break;
        asm volatile("s_waitcnt lgkmcnt(0)" ::: "memory");
        barrier_raw();
        jb = jn;
        cur ^= 1;
    }

    float inv = 1.f / l_i;
    size_t orow = (size_t)(ib * 64 + w * 16 + l15) * HID + hq * 96;
#pragma unroll
    for (int dt = 0; dt < 6; ++dt) {
        int2 pkd;
        pkd.x = (int)packbf2(acc_o[dt][0] * inv, acc_o[dt][1] * inv);
        pkd.y = (int)packbf2(acc_o[dt][2] * inv, acc_o[dt][3] * inv);
        *(int2*)(out + orow + dt * 16 + quad * 4) = pkd;
    }
}

extern "C" void kernel_launch(void* const* d_in, const int* in_sizes, int n_in,
                              void* d_out, int out_size, void* d_ws, size_t ws_size,
                              hipStream_t stream) {
    const float* hidden  = (const float*)d_in[0];
    const float* cosb    = (const float*)d_in[1];
    const float* sinb    = (const float*)d_in[2];
    const float* qkv_w   = (const float*)d_in[3];
    const float* o_w     = (const float*)d_in[4];
    const float* gate_wq = (const float*)d_in[5];
    const float* gate_wk = (const float*)d_in[6];
    float* out = (float*)d_out;

    char* ws = (char*)d_ws;
    ushort_t* qkv_bf   = (ushort_t*)ws;                    // 18,874,368 B
    float*    qkv_f32K = (float*)(ws + 18874368);          //  6,291,456 B
    ushort_t* h_bf     = (ushort_t*)(ws + 25165824);       // 12,582,912 B (reused as Qb)
    ushort_t* w1t      = (ushort_t*)(ws + 37748736);       // 28,311,552 B (reused as o_wt)
    ushort_t* attn_out = (ushort_t*)(ws + 66060288);       // 12,582,912 B
    ushort_t* Kb       = (ushort_t*)(ws + 78643200);       //  3,145,728 B
    ushort_t* Vtb      = (ushort_t*)(ws + 81788928);       //  3,145,728 B
    float*    k_gate   = (float*)(ws + 84934656);          //    131,072 B
    float*    q_gate   = (float*)(ws + 85065728);          //    131,072 B
    int*      mask     = (int*)(ws + 85196800);            //     32,768 B
    ushort_t* Qb   = h_bf;            // alias: h_bf dead after gemm1
    ushort_t* o_wt = w1t;             // alias: w1t dead after gemm1

    // prep1: hidden->bf16 + qkv_w transpose (fused, independent blocks)
    prep1<<<9600, 256, 0, stream>>>(hidden, h_bf, qkv_w, w1t);
    // 1. QKV projection -> bf16 qkv (+ f32 K-section for exact gate numerics)
    gemm_bf16<<<dim3(QKV_N / 128, S_LEN / 128), 256, 0, stream>>>(
        h_bf, w1t, nullptr, qkv_bf, qkv_f32K, S_LEN, QKV_N, HID, 1);
    // 2. fused pools + gate GEMVs + o_w transpose (o_wt aliases w1t — dead now)
    pool_gate_kernel<<<2560, 256, 0, stream>>>(qkv_f32K, qkv_bf,
                                               gate_wk, gate_wq, k_gate, q_gate,
                                               o_w, o_wt);
    // 3. block mask
    blockmask_kernel<<<dim3(NKV, NB), 256, 0, stream>>>(q_gate, k_gate, mask);
    // 4. prep2: RoPE q/k + V transpose
    prep2<<<15616, 256, 0, stream>>>(qkv_bf, cosb, sinb, Qb, Kb, Vtb);
    // 5. block-sparse flash attention -> bf16
    attn_mfma<<<dim3(NHEAD, NB), 256, 0, stream>>>(Qb, Kb, Vtb, mask, attn_out);
    // 6. output projection -> f32 out
    gemm_bf16<<<dim3(HID / 128, S_LEN / 128), 256, 0, stream>>>(
        attn_out, o_wt, out, nullptr, nullptr, S_LEN, HID, HID, 0);
}

// Round 11
// 375.515 us; speedup vs baseline: 1.0666x; 1.0666x over previous
//
#include <hip/hip_runtime.h>
#include <hip/hip_bf16.h>
#include <math.h>

#define S_LEN 2048
#define HID 3072
#define NHEAD 32
#define NKV 8
#define HDIM 96
#define QKV_N 4608   // 32*96 + 2*8*96
#define NB 32        // S/64 blocks
#define GHDIM 128
#define KOFF 3072    // K section start col
#define VOFF 3840    // V section start col

typedef __attribute__((ext_vector_type(8))) short bf16x8;
typedef __attribute__((ext_vector_type(4))) short bf16x4;
typedef __attribute__((ext_vector_type(4))) float f32x4;
typedef unsigned short ushort_t;

// 1/sqrt(96) * log2(e): Q pre-scaled so softmax runs in exp2 domain
#define SCALE2 0.14724444754f

__device__ __forceinline__ unsigned short f2bf(float x) {
    unsigned u = __float_as_uint(x);
    u += 0x7fffu + ((u >> 16) & 1u);
    return (unsigned short)(u >> 16);
}
__device__ __forceinline__ unsigned packbf2(float a, float b) {
    return (unsigned)f2bf(a) | ((unsigned)f2bf(b) << 16);
}
__device__ __forceinline__ float bf2f(ushort_t u) {
    return __uint_as_float(((unsigned)u) << 16);
}

#define GLOBAL_AS __attribute__((address_space(1)))
#define LDS_AS __attribute__((address_space(3)))
__device__ __forceinline__ void gl_lds16(const void* g, void* l) {
    __builtin_amdgcn_global_load_lds((const GLOBAL_AS unsigned int*)g,
                                     (LDS_AS unsigned int*)l, 16, 0, 0);
}
__device__ __forceinline__ void barrier_raw() {
    asm volatile("s_barrier" ::: "memory");
}

// ============ bf16 MFMA GEMM (m97 structure): A[M,K] @ Bt[N,K]^T ============
// R1-exact: proven 77.9us local optimum. Design space fully measured:
// dbuf64K+swz=111, dbuf32K/BK32=86.5, BM64=84.5, global-B=172, BK96=87.6,
// dbuf64K-noswz=109.7 (R10 clean A/B: occupancy cost of 64KB LDS dominates
// any prefetch gain in the 2-phase structure). Do not perturb further.
// mode 0: C f32. mode 1 (QKV): Cbf bf16 [M,N]; K-section cols also f32 -> CfK.
__global__ __launch_bounds__(256, 4) void gemm_bf16(const ushort_t* __restrict__ A,
                                                    const ushort_t* __restrict__ Bt,
                                                    float* __restrict__ C,
                                                    ushort_t* __restrict__ Cbf,
                                                    float* __restrict__ CfK,
                                                    int M, int N, int K, int mode) {
    __shared__ ushort_t As[128 * 64];
    __shared__ ushort_t Bs[128 * 64];
    const int tid = threadIdx.x;
    const int lane = tid & 63;
    const int w = tid >> 6;
    const int wm = (w >> 1) * 64;
    const int wn = (w & 1) * 64;
    const int l15 = lane & 15;
    const int quad = lane >> 4;
    const int m0 = blockIdx.y * 128;
    const int n0 = blockIdx.x * 128;

    f32x4 acc[4][4] = {};

    for (int k0 = 0; k0 < K; k0 += 64) {
        __syncthreads();
#pragma unroll
        for (int j = 0; j < 4; ++j) {
            int s = j * 256 + w * 64 + lane;
            int row = s >> 3;
            int kc = (s & 7) ^ (row & 7);
            gl_lds16(A + (size_t)(m0 + row) * K + k0 + kc * 8,
                     &As[(j * 256 + w * 64) * 8]);
        }
#pragma unroll
        for (int j = 0; j < 4; ++j) {
            int s = j * 256 + w * 64 + lane;
            int row = s >> 3;
            int kc = (s & 7) ^ (row & 7);
            gl_lds16(Bt + (size_t)(n0 + row) * K + k0 + kc * 8,
                     &Bs[(j * 256 + w * 64) * 8]);
        }
        __syncthreads();
        bf16x8 af[2][4], bf[2][4];
#pragma unroll
        for (int mt = 0; mt < 4; ++mt) {
            int row = wm + mt * 16 + l15;
            int rx = row & 7;
#pragma unroll
            for (int ph = 0; ph < 2; ++ph)
                af[ph][mt] = *(const bf16x8*)&As[(row * 8 + ((ph * 4 + quad) ^ rx)) * 8];
        }
#pragma unroll
        for (int nt = 0; nt < 4; ++nt) {
            int row = wn + nt * 16 + l15;
            int rx = row & 7;
#pragma unroll
            for (int ph = 0; ph < 2; ++ph)
                bf[ph][nt] = *(const bf16x8*)&Bs[(row * 8 + ((ph * 4 + quad) ^ rx)) * 8];
        }
#pragma unroll
        for (int ph = 0; ph < 2; ++ph)
#pragma unroll
            for (int mt = 0; mt < 4; ++mt)
#pragma unroll
                for (int nt = 0; nt < 4; ++nt)
                    acc[mt][nt] = __builtin_amdgcn_mfma_f32_16x16x32_bf16(
                        af[ph][mt], bf[ph][nt], acc[mt][nt], 0, 0, 0);
    }
    if (mode == 0) {
#pragma unroll
        for (int mt = 0; mt < 4; ++mt)
#pragma unroll
            for (int nt = 0; nt < 4; ++nt)
#pragma unroll
                for (int r = 0; r < 4; ++r) {
                    int row = m0 + wm + mt * 16 + quad * 4 + r;
                    int col = n0 + wn + nt * 16 + l15;
                    C[(size_t)row * N + col] = acc[mt][nt][r];
                }
    } else {
        const bool isK = (n0 >= KOFF) && (n0 < VOFF);
#pragma unroll
        for (int mt = 0; mt < 4; ++mt)
#pragma unroll
            for (int nt = 0; nt < 4; ++nt)
#pragma unroll
                for (int r = 0; r < 4; ++r) {
                    int row = m0 + wm + mt * 16 + quad * 4 + r;
                    int col = n0 + wn + nt * 16 + l15;
                    Cbf[(size_t)row * N + col] = f2bf(acc[mt][nt][r]);
                    if (isK) CfK[(size_t)row * 768 + col - KOFF] = acc[mt][nt][r];
                }
    }
}

// ---------------- shared bodies for fused prep kernels ------------------------
__device__ __forceinline__ void conv_body(const float* __restrict__ X,
                                          ushort_t* __restrict__ Y, int i) {
    const float4 v = *(const float4*)(X + (size_t)i * 4);
    int2 p;
    p.x = (int)packbf2(v.x, v.y);
    p.y = (int)packbf2(v.z, v.w);
    *(int2*)(Y + (size_t)i * 4) = p;
}

__device__ __forceinline__ void transpose_body(const float* __restrict__ W,
                                               ushort_t* __restrict__ Wt,
                                               int K, int N, int k0, int n0, int tid) {
    __shared__ float Ts[64][65];
    {
        int r = tid >> 2, cq = tid & 3;
#pragma unroll
        for (int i = 0; i < 4; ++i) {
            int c = cq * 16 + i * 4;
            const float4 v = *(const float4*)(W + (size_t)(k0 + r) * N + n0 + c);
            Ts[r][c] = v.x; Ts[r][c + 1] = v.y; Ts[r][c + 2] = v.z; Ts[r][c + 3] = v.w;
        }
    }
    __syncthreads();
#pragma unroll
    for (int it = 0; it < 2; ++it) {
        int n = (tid >> 3) + it * 32;
        int kc = tid & 7;
        int4 r;
        r.x = (int)(packbf2(Ts[kc * 8 + 0][n], Ts[kc * 8 + 1][n]));
        r.y = (int)(packbf2(Ts[kc * 8 + 2][n], Ts[kc * 8 + 3][n]));
        r.z = (int)(packbf2(Ts[kc * 8 + 4][n], Ts[kc * 8 + 5][n]));
        r.w = (int)(packbf2(Ts[kc * 8 + 6][n], Ts[kc * 8 + 7][n]));
        *(int4*)(Wt + (size_t)(n0 + n) * K + k0 + kc * 8) = r;
    }
}

// prep1: hidden f32->bf16 (blocks 0..6143) + qkv_w transpose (blocks 6144..9599)
__global__ __launch_bounds__(256) void prep1(const float* __restrict__ hidden,
                                             ushort_t* __restrict__ h_bf,
                                             const float* __restrict__ qkv_w,
                                             ushort_t* __restrict__ w1t) {
    int id = blockIdx.x;
    int tid = threadIdx.x;
    if (id < 6144) {
        conv_body(hidden, h_bf, id * 256 + tid);
    } else {
        int r = id - 6144;              // 72 x 48
        transpose_body(qkv_w, w1t, HID, QKV_N, (r / 72) * 64, (r % 72) * 64, tid);
    }
}

// prep2: RoPE q/k from bf16 qkv (0..15359) + V transpose (15360..15615)
//        (o_w transpose lives in pool_gate launch — overlaps the gate pools)
__global__ __launch_bounds__(256) void prep2(const ushort_t* __restrict__ qkv_bf,
                                             const float* __restrict__ cosb,
                                             const float* __restrict__ sinb,
                                             ushort_t* __restrict__ Qb,
                                             ushort_t* __restrict__ Kb,
                                             ushort_t* __restrict__ Vtb) {
    int id = blockIdx.x;
    int tid = threadIdx.x;
    if (id < 15360) {
        int idx = id * 256 + tid;   // S*40*48
        int d = idx % 48;
        int tmp = idx / 48;
        int head = tmp % 40;
        int s = tmp / 40;
        float c0 = cosb[s * 96 + d], c1 = cosb[s * 96 + d + 48];
        float s0 = sinb[s * 96 + d], s1 = sinb[s * 96 + d + 48];
        if (head < 32) {
            size_t base = (size_t)s * QKV_N + head * 96;
            float x0 = bf2f(qkv_bf[base + d]), x1 = bf2f(qkv_bf[base + d + 48]);
            size_t ob = (size_t)s * HID + head * 96;
            Qb[ob + d] = f2bf((x0 * c0 - x1 * s0) * SCALE2);
            Qb[ob + d + 48] = f2bf((x1 * c1 + x0 * s1) * SCALE2);
        } else {
            int hh = head - 32;
            size_t base = (size_t)s * QKV_N + KOFF + hh * 96;
            float x0 = bf2f(qkv_bf[base + d]), x1 = bf2f(qkv_bf[base + d + 48]);
            size_t ob = ((size_t)hh * S_LEN + s) * 96;
            Kb[ob + d] = f2bf(x0 * c0 - x1 * s0);
            Kb[ob + d + 48] = f2bf(x1 * c1 + x0 * s1);
        }
    } else {
        int r = id - 15360;
        int ibk = r & 31, h = r >> 5;
        __shared__ ushort_t Vs[64][104];   // 208B rows, 16B aligned
        {
            int rr = tid >> 2, seg = tid & 3;
#pragma unroll
            for (int j = 0; j < 3; ++j) {
                int c = seg * 24 + j * 8;
                const int4 v = *(const int4*)(qkv_bf + (size_t)(ibk * 64 + rr) * QKV_N +
                                              VOFF + h * 96 + c);
                *(int4*)&Vs[rr][c] = v;
            }
        }
        __syncthreads();
#pragma unroll
        for (int it = 0; it < 3; ++it) {
            int s = tid + it * 256;       // 768 = 96 d x 8 tc
            int d = s >> 3, tc = s & 7;
            int4 o;
            o.x = (int)Vs[tc * 8 + 0][d] | ((int)Vs[tc * 8 + 1][d] << 16);
            o.y = (int)Vs[tc * 8 + 2][d] | ((int)Vs[tc * 8 + 3][d] << 16);
            o.z = (int)Vs[tc * 8 + 4][d] | ((int)Vs[tc * 8 + 5][d] << 16);
            o.w = (int)Vs[tc * 8 + 6][d] | ((int)Vs[tc * 8 + 7][d] << 16);
            *(int4*)(Vtb + ((size_t)h * 96 + d) * S_LEN + ibk * 64 + tc * 8) = o;
        }
    }
}

// ---------------- fused pools + gate GEMVs + o_w transpose --------------------
// blocks 0..255: pools+GEMVs (nb=id&31, h=id>>5). blocks 256..2559: o_w
// transpose (independent; fills the machine during the latency-bound gates —
// R10 accounting: this fusion is worth ~45us of end-to-end overlap).
__global__ __launch_bounds__(256) void pool_gate_kernel(const float* __restrict__ qkvK,
                                                        const ushort_t* __restrict__ qkv_bf,
                                                        const float* __restrict__ gate_wk,
                                                        const float* __restrict__ gate_wq,
                                                        float* __restrict__ k_gate,
                                                        float* __restrict__ q_gate,
                                                        const float* __restrict__ o_w,
                                                        ushort_t* __restrict__ o_wt) {
    int id = blockIdx.x;
    int tid = threadIdx.x;
    if (id >= 256) {
        int r = id - 256;               // 48 x 48
        transpose_body(o_w, o_wt, HID, HID, (r / 48) * 64, (r % 48) * 64, tid);
        return;
    }
    int nb = id & 31, h = id >> 5;
    __shared__ float poolk[192];
    __shared__ float poolq[96];
    __shared__ float poolq2[8][96];
    if (tid < 128) {
        if (tid < 96) {
            float s = 0.f, mx = -1e30f;
            for (int i = 0; i < 64; i++) {
                float v = qkvK[(size_t)(nb * 64 + i) * 768 + h * 96 + tid];
                s += v;
                mx = fmaxf(mx, v);
            }
            poolk[tid] = s * (1.f / 64.f);
            poolk[96 + tid] = mx;
        }
    } else {
        int t2 = tid - 128;
        if (t2 < 96) {
            int o = t2 % 12;       // element octet (8 bf16)
            int hf = t2 / 12;      // i-range hf*8 .. hf*8+7
            float part[8] = {};
            for (int ii = 0; ii < 8; ++ii) {
                int i = hf * 8 + ii;
                const ushort_t* rp = qkv_bf + (size_t)(nb * 64 + i) * QKV_N +
                                     h * 4 * 96 + o * 8;
#pragma unroll
                for (int g = 0; g < 4; ++g) {
                    bf16x8 v = *(const bf16x8*)(rp + g * 96);
#pragma unroll
                    for (int j = 0; j < 8; ++j) part[j] += bf2f((ushort_t)v[j]);
                }
            }
#pragma unroll
            for (int j = 0; j < 8; ++j) poolq2[hf][o * 8 + j] = part[j];
        }
    }
    __syncthreads();
    if (tid >= 128 && tid < 224) {
        int t2 = tid - 128;
        float s = 0.f;
#pragma unroll
        for (int hf = 0; hf < 8; ++hf) s += poolq2[hf][t2];
        poolq[t2] = s * (1.f / 256.f);
    }
    __syncthreads();
    if (tid < 128) {
        float acc = 0.f;
        for (int e = 0; e < 192; e++) acc += poolk[e] * gate_wk[e * GHDIM + tid];
        k_gate[(size_t)(nb * NKV + h) * GHDIM + tid] = acc;
    } else {
        int t2 = tid - 128;
        float acc = 0.f;
        for (int e = 0; e < 96; e++) acc += poolq[e] * gate_wq[e * GHDIM + t2];
        q_gate[(size_t)(nb * NKV + h) * GHDIM + t2] = acc;
    }
}

// ---------------- block gate logits -> softmax -> threshold mask --------------
// v2: 256 threads; 8 lanes per kv-block dot (16 MACs each + shfl_xor reduce)
__global__ __launch_bounds__(256) void blockmask_kernel(const float* __restrict__ q_gate,
                                                        const float* __restrict__ k_gate,
                                                        int* __restrict__ mask) {
    int h = blockIdx.x, qb = blockIdx.y;
    int tid = threadIdx.x;
    __shared__ float logits[32];
    int kb = tid >> 3, e8 = tid & 7;
    float acc = 0.f;
    if (kb <= qb) {
        const float* qg = &q_gate[(size_t)(qb * NKV + h) * GHDIM];
        const float* kg = &k_gate[(size_t)(kb * NKV + h) * GHDIM];
#pragma unroll
        for (int i = 0; i < 16; ++i) {
            int e = e8 * 16 + i;
            acc += qg[e] * kg[e];
        }
    }
    acc += __shfl_xor(acc, 1);
    acc += __shfl_xor(acc, 2);
    acc += __shfl_xor(acc, 4);
    if (e8 == 0) logits[kb] = (kb <= qb) ? acc * 0.08838834764831845f : -1e30f;
    __syncthreads();
    if (tid < 32) {
        float mx = -1e30f;
        for (int j = 0; j <= qb; j++) mx = fmaxf(mx, logits[j]);
        float sum = 0.f;
        for (int j = 0; j <= qb; j++) sum += __expf(logits[j] - mx);
        float p = (tid <= qb) ? __expf(logits[tid] - mx) / sum : 0.f;
        int m = ((p >= 0.03f) && (tid <= qb)) || (tid == qb);
        mask[(h * NB + qb) * NB + tid] = m;
    }
}

// ============ MFMA block-sparse flash attention v3 + T5 setprio ========
__global__ __launch_bounds__(256) void attn_mfma(const ushort_t* __restrict__ Qb,
                                                 const ushort_t* __restrict__ Kb,
                                                 const ushort_t* __restrict__ Vtb,
                                                 const int* __restrict__ mask,
                                                 ushort_t* __restrict__ out) {
    const int hq = blockIdx.x;
    const int ib = NB - 1 - (int)blockIdx.y;
    const int h = hq >> 2;
    const int tid = threadIdx.x;
    const int lane = tid & 63;
    const int w = tid >> 6;
    const int l15 = lane & 15;
    const int quad = lane >> 4;

    __shared__ ushort_t KsL[2][64 * 96];
    __shared__ ushort_t VtL[2][96 * 64];

    int pk[3];
    {
        int b0 = quad + (l15 & 7);
#pragma unroll
        for (int ks = 0; ks < 3; ++ks) {
            int p = b0 + ks * 4;
            if (p >= 12) p -= 12;
            if (p >= 12) p -= 12;
            pk[ks] = p;
        }
    }

    bf16x8 qf[3];
    {
        const ushort_t* qp = Qb + (size_t)(ib * 64 + w * 16 + l15) * HID + hq * 96;
#pragma unroll
        for (int ks = 0; ks < 3; ++ks)
            qf[ks] = *(const bf16x8*)(qp + ks * 32 + quad * 8);
    }

    const ushort_t* kbase = Kb + (size_t)h * S_LEN * 96;
    const ushort_t* vbase = Vtb + (size_t)h * 96 * S_LEN;

    unsigned long long bits =
        __ballot((lane <= ib) && (mask[(h * NB + ib) * NB + (lane & 31)] != 0));

    float m_i = -1e30f, l_i = 0.f;
    f32x4 acc_o[6] = {};

    auto stage = [&](int jb, int buf) {
#pragma unroll
        for (int j = 0; j < 3; ++j) {
            int s = j * 256 + w * 64 + lane;
            int t = (s * 2731) >> 15;
            int cpos = s - t * 12;
            int c = cpos - (t & 7);
            if (c < 0) c += 12;
            gl_lds16(kbase + (size_t)(jb * 64 + t) * 96 + c * 8,
                     &KsL[buf][(j * 256 + w * 64) * 8]);
        }
#pragma unroll
        for (int j = 0; j < 3; ++j) {
            int s = j * 256 + w * 64 + lane;
            int d = s >> 3;
            int tc = (s & 7) ^ (d & 7);
            gl_lds16(vbase + (size_t)d * S_LEN + jb * 64 + tc * 8,
                     &VtL[buf][(j * 256 + w * 64) * 8]);
        }
    };

    int jb = (int)__builtin_ctzll(bits);
    bits &= bits - 1;
    stage(jb, 0);
    int cur = 0;

    while (true) {
        int jn = -1;
        if (bits) {
            jn = (int)__builtin_ctzll(bits);
            bits &= bits - 1;
        }
        if (jn >= 0) {
            stage(jn, cur ^ 1);
            asm volatile("s_waitcnt vmcnt(6)" ::: "memory");
        } else {
            asm volatile("s_waitcnt vmcnt(0)" ::: "memory");
        }
        barrier_raw();

        const ushort_t* Kc = KsL[cur];
        const ushort_t* Vc = VtL[cur];

        f32x4 st[4] = {};
        __builtin_amdgcn_s_setprio(1);
#pragma unroll
        for (int ks = 0; ks < 3; ++ks)
#pragma unroll
            for (int nt = 0; nt < 4; ++nt) {
                bf16x8 kb = *(const bf16x8*)&Kc[(nt * 16 + l15) * 96 + pk[ks] * 8];
                st[nt] = __builtin_amdgcn_mfma_f32_16x16x32_bf16(kb, qf[ks], st[nt], 0, 0, 0);
            }
        __builtin_amdgcn_s_setprio(0);
        if (jb == ib) {
            int q = w * 16 + l15;
#pragma unroll
            for (int nt = 0; nt < 4; ++nt)
#pragma unroll
                for (int r = 0; r < 4; ++r)
                    if ((nt * 16 + quad * 4 + r) > q) st[nt][r] = -1e30f;
        }
        float mx = -1e30f;
#pragma unroll
        for (int nt = 0; nt < 4; ++nt)
#pragma unroll
            for (int r = 0; r < 4; ++r) mx = fmaxf(mx, st[nt][r]);
        mx = fmaxf(mx, __shfl_xor(mx, 16));
        mx = fmaxf(mx, __shfl_xor(mx, 32));
        float mnew = fmaxf(m_i, mx);
        float alpha = __builtin_amdgcn_exp2f(m_i - mnew);
        float ps = 0.f;
#pragma unroll
        for (int nt = 0; nt < 4; ++nt)
#pragma unroll
            for (int r = 0; r < 4; ++r) {
                float p = __builtin_amdgcn_exp2f(st[nt][r] - mnew);
                st[nt][r] = p;
                ps += p;
            }
        ps += __shfl_xor(ps, 16);
        ps += __shfl_xor(ps, 32);
        l_i = l_i * alpha + ps;
        m_i = mnew;
#pragma unroll
        for (int t = 0; t < 6; ++t)
#pragma unroll
            for (int r = 0; r < 4; ++r) acc_o[t][r] *= alpha;
        bf16x4 pf[4];
#pragma unroll
        for (int kblk = 0; kblk < 4; ++kblk) {
            union { bf16x4 v; unsigned u[2]; } pb;
            pb.u[0] = packbf2(st[kblk][0], st[kblk][1]);
            pb.u[1] = packbf2(st[kblk][2], st[kblk][3]);
            pf[kblk] = pb.v;
        }
        __builtin_amdgcn_s_setprio(1);
#pragma unroll
        for (int kblk = 0; kblk < 4; ++kblk) {
            int cchunk = kblk * 2 + (quad >> 1);
            int eoff = (quad & 1) * 4;
#pragma unroll
            for (int dt = 0; dt < 6; ++dt) {
                int d = dt * 16 + l15;
                bf16x4 vf = *(const bf16x4*)&Vc[(d * 8 + (cchunk ^ (d & 7))) * 8 + eoff];
                acc_o[dt] = __builtin_amdgcn_mfma_f32_16x16x16bf16_1k(
                    vf, pf[kblk], acc_o[dt], 0, 0, 0);
            }
        }
        __builtin_amdgcn_s_setprio(0);

        if (jn < 0) break;
        asm volatile("s_waitcnt lgkmcnt(0)" ::: "memory");
        barrier_raw();
        jb = jn;
        cur ^= 1;
    }

    float inv = 1.f / l_i;
    size_t orow = (size_t)(ib * 64 + w * 16 + l15) * HID + hq * 96;
#pragma unroll
    for (int dt = 0; dt < 6; ++dt) {
        int2 pkd;
        pkd.x = (int)packbf2(acc_o[dt][0] * inv, acc_o[dt][1] * inv);
        pkd.y = (int)packbf2(acc_o[dt][2] * inv, acc_o[dt][3] * inv);
        *(int2*)(out + orow + dt * 16 + quad * 4) = pkd;
    }
}

extern "C" void kernel_launch(void* const* d_in, const int* in_sizes, int n_in,
                              void* d_out, int out_size, void* d_ws, size_t ws_size,
                              hipStream_t stream) {
    const float* hidden  = (const float*)d_in[0];
    const float* cosb    = (const float*)d_in[1];
    const float* sinb    = (const float*)d_in[2];
    const float* qkv_w   = (const float*)d_in[3];
    const float* o_w     = (const float*)d_in[4];
    const float* gate_wq = (const float*)d_in[5];
    const float* gate_wk = (const float*)d_in[6];
    float* out = (float*)d_out;

    char* ws = (char*)d_ws;
    ushort_t* qkv_bf   = (ushort_t*)ws;                    // 18,874,368 B
    float*    qkv_f32K = (float*)(ws + 18874368);          //  6,291,456 B
    ushort_t* h_bf     = (ushort_t*)(ws + 25165824);       // 12,582,912 B (reused as Qb)
    ushort_t* w1t      = (ushort_t*)(ws + 37748736);       // 28,311,552 B (reused as o_wt)
    ushort_t* attn_out = (ushort_t*)(ws + 66060288);       // 12,582,912 B
    ushort_t* Kb       = (ushort_t*)(ws + 78643200);       //  3,145,728 B
    ushort_t* Vtb      = (ushort_t*)(ws + 81788928);       //  3,145,728 B
    float*    k_gate   = (float*)(ws + 84934656);          //    131,072 B
    float*    q_gate   = (float*)(ws + 85065728);          //    131,072 B
    int*      mask     = (int*)(ws + 85196800);            //     32,768 B
    ushort_t* Qb   = h_bf;            // alias: h_bf dead after gemm1
    ushort_t* o_wt = w1t;             // alias: w1t dead after gemm1

    // prep1: hidden->bf16 + qkv_w transpose (fused, independent blocks)
    prep1<<<9600, 256, 0, stream>>>(hidden, h_bf, qkv_w, w1t);
    // 1. QKV projection -> bf16 qkv (+ f32 K-section for exact gate numerics)
    gemm_bf16<<<dim3(QKV_N / 128, S_LEN / 128), 256, 0, stream>>>(
        h_bf, w1t, nullptr, qkv_bf, qkv_f32K, S_LEN, QKV_N, HID, 1);
    // 2. fused pools + gate GEMVs + o_w transpose (o_wt aliases w1t — dead now)
    pool_gate_kernel<<<2560, 256, 0, stream>>>(qkv_f32K, qkv_bf,
                                               gate_wk, gate_wq, k_gate, q_gate,
                                               o_w, o_wt);
    // 3. block mask
    blockmask_kernel<<<dim3(NKV, NB), 256, 0, stream>>>(q_gate, k_gate, mask);
    // 4. prep2: RoPE q/k + V transpose
    prep2<<<15616, 256, 0, stream>>>(qkv_bf, cosb, sinb, Qb, Kb, Vtb);
    // 5. block-sparse flash attention -> bf16
    attn_mfma<<<dim3(NHEAD, NB), 256, 0, stream>>>(Qb, Kb, Vtb, mask, attn_out);
    // 6. output projection -> f32 out
    gemm_bf16<<<dim3(HID / 128, S_LEN / 128), 256, 0, stream>>>(
        attn_out, o_wt, out, nullptr, nullptr, S_LEN, HID, HID, 0);
}